// Round 5
// baseline (135.217 us; speedup 1.0000x reference)
//
#include <hip/hip_runtime.h>
#include <stdint.h>
#include <stddef.h>

#define BB 16
#define TT 2048
#define CC 64

typedef __attribute__((ext_vector_type(8))) short short8;
typedef __attribute__((ext_vector_type(4))) short s16x4;
typedef __attribute__((ext_vector_type(4))) float f32x4;
typedef __attribute__((ext_vector_type(16))) float f32x16;

#if defined(__has_builtin)
#if __has_builtin(__builtin_amdgcn_exp2f)
#define EXP2(x) __builtin_amdgcn_exp2f(x)
#else
#define EXP2(x) exp2f(x)
#endif
#else
#define EXP2(x) exp2f(x)
#endif

// round-to-nearest-even f32 -> bf16 bit pattern
static __device__ __forceinline__ unsigned short f2bf(float f) {
  union { float f; unsigned int u; } v; v.f = f;
  unsigned int u = v.u;
  return (unsigned short)((u + 0x7FFFu + ((u >> 16) & 1u)) >> 16);
}

// T12 pack: 8 f32 (this lane's half of a 16-k strip) -> PV A-fragment.
static __device__ __forceinline__ short8 pack_swap(
    float a0, float a1, float a2, float a3,
    float a4, float a5, float a6, float a7) {
  unsigned X, Z, Y, W;
  asm("v_cvt_pk_bf16_f32 %0, %1, %2" : "=v"(X) : "v"(a0), "v"(a1));
  asm("v_cvt_pk_bf16_f32 %0, %1, %2" : "=v"(Z) : "v"(a2), "v"(a3));
  asm("v_cvt_pk_bf16_f32 %0, %1, %2" : "=v"(Y) : "v"(a4), "v"(a5));
  asm("v_cvt_pk_bf16_f32 %0, %1, %2" : "=v"(W) : "v"(a6), "v"(a7));
  asm("v_permlane32_swap_b32 %0, %1" : "+v"(X), "+v"(Y));
  asm("v_permlane32_swap_b32 %0, %1" : "+v"(Z), "+v"(W));
  union { unsigned u[4]; short8 s; } u;
  u.u[0] = X; u.u[1] = Z; u.u[2] = Y; u.u[3] = W;
  return u.s;
}

// ---------------------------------------------------------------------------
// Prep: xb = bf16(x) [B,T,C]; xbT = transposed [B,C,T]; sq = row sum of sq.
// ---------------------------------------------------------------------------
__global__ __launch_bounds__(256, 4) void prep_kernel(
    const float* __restrict__ x, unsigned short* __restrict__ xb,
    unsigned short* __restrict__ xbT, float* __restrict__ sq)
{
  __shared__ unsigned short tile[16 * 68];
  const int b   = blockIdx.x >> 7;
  const int t0  = (blockIdx.x & 127) << 4;
  const int tid = threadIdx.x;
  const int r   = tid >> 4;
  const int cg  = tid & 15;
  const int c4  = cg * 4;

  const size_t idx = (size_t)(b * TT + t0 + r) * CC + c4;
  const f32x4 v = *(const f32x4*)(x + idx);
  float ssq = v[0]*v[0] + v[1]*v[1] + v[2]*v[2] + v[3]*v[3];

  s16x4 hv;
  hv[0] = (short)f2bf(v[0]); hv[1] = (short)f2bf(v[1]);
  hv[2] = (short)f2bf(v[2]); hv[3] = (short)f2bf(v[3]);
  *(s16x4*)(xb + idx) = hv;
  *(s16x4*)(&tile[r * 68 + c4]) = hv;

  ssq += __shfl_xor(ssq, 1); ssq += __shfl_xor(ssq, 2);
  ssq += __shfl_xor(ssq, 4); ssq += __shfl_xor(ssq, 8);
  if (cg == 0) sq[(size_t)b * TT + t0 + r] = ssq;
  __syncthreads();

  const int c = tid >> 2, tq = tid & 3;
  s16x4 o;
#pragma unroll
  for (int k = 0; k < 4; ++k) o[k] = (short)tile[(tq * 4 + k) * 68 + c];
  *(s16x4*)(xbT + (size_t)(b * CC + c) * TT + t0 + tq * 4) = o;
}

// ---------------------------------------------------------------------------
// attn v3: barrier-free main loop. All MFMA fragments loaded directly from
// global (L1/L2-resident): swapped QK^T A-frag = contiguous row-slice of xb,
// PV B-frag = contiguous row-slice of xbT, sq terms = f32x4 loads. Waves run
// free; only the final ws-reduction syncs through LDS.
// ---------------------------------------------------------------------------
__global__ __launch_bounds__(256, 2) void attn_kernel(
    const float* __restrict__ x, const unsigned short* __restrict__ xb,
    const unsigned short* __restrict__ xbT, const float* __restrict__ sq,
    const float* __restrict__ rsig, const float* __restrict__ marg,
    float* __restrict__ out)
{
  __shared__ float Red[2][32 * 64];

  const int bid = ((blockIdx.x & 7) << 6) | (blockIdx.x >> 3);  // XCD swizzle
  const int b   = bid >> 5;
  const int qb  = (bid & 31) << 6;
  const int tid = threadIdx.x;
  const int w = tid >> 6, lane = tid & 63;
  const int l31 = lane & 31, hi1 = lane >> 5;
  const int wq = w & 1, ws = w >> 1;

  const float L2E = 1.44269504088896f;
  const float rl2 = -rsig[0] * L2E;
  const float ml2 = marg[0] * L2E;

  const unsigned short* xb_b  = xb  + (size_t)b * TT * CC;
  const unsigned short* xbT_b = xbT + (size_t)b * CC * TT;
  const float* sq_b = sq + (size_t)b * TT;

  const int q0w = qb + wq * 32;

  // Q B-fragments: col q = q0w + l31, k = c = kc*16 + hi1*8 + j
  short8 qf[4];
#pragma unroll
  for (int kc = 0; kc < 4; ++kc)
    qf[kc] = *(const short8*)(xb_b + (size_t)(q0w + l31) * CC + kc * 16 + hi1 * 8);
  const float aq = sq_b[q0w + l31];

  f32x16 oacc[2];
#pragma unroll
  for (int ct = 0; ct < 2; ++ct)
#pragma unroll
    for (int i = 0; i < 16; ++i) oacc[ct][i] = 0.f;

  // per-wave global fragment bases
  const unsigned short* kbase  = xb_b  + (size_t)(ws * 32 + l31) * CC + hi1 * 8;
  const unsigned short* vbase0 = xbT_b + (size_t)(l31) * TT      + ws * 32 + hi1 * 8;
  const unsigned short* vbase1 = xbT_b + (size_t)(32 + l31) * TT + ws * 32 + hi1 * 8;
  const float* sqp = sq_b + ws * 32 + 4 * hi1;

  const int dtile = (qb + wq * 32 - ws * 32) >> 6;   // t of diagonal quadrant
  const bool dvalid = ((qb + wq * 32 - ws * 32) & 63) == 0 &&
                      dtile >= 0 && dtile < 32;

#pragma unroll 2
  for (int t = 0; t < 32; ++t) {
    const int tb = t * 64;

    // K A-frags (row tb+ws*32+l31, contiguous 16B)
    short8 kf[4];
#pragma unroll
    for (int kc = 0; kc < 4; ++kc)
      kf[kc] = *(const short8*)(kbase + (size_t)tb * CC + kc * 16);

    // s sums of squares: 4 x f32x4
    f32x4 sqv[4];
#pragma unroll
    for (int ch = 0; ch < 4; ++ch)
      sqv[ch] = *(const f32x4*)(sqp + tb + ch * 8);

    // V B-frags (row c of xbT, contiguous 16B), independent of QK chain
    short8 vf[2][2];
#pragma unroll
    for (int kk = 0; kk < 2; ++kk) {
      vf[0][kk] = *(const short8*)(vbase0 + tb + kk * 16);
      vf[1][kk] = *(const short8*)(vbase1 + tb + kk * 16);
    }

    // QK^T swapped: D[s][q]
    f32x16 sac;
#pragma unroll
    for (int i = 0; i < 16; ++i) sac[i] = 0.f;
#pragma unroll
    for (int kc = 0; kc < 4; ++kc)
      sac = __builtin_amdgcn_mfma_f32_32x32x16_bf16(kf[kc], qf[kc], sac, 0, 0, 0);

    // Gaussian kernel
    float p[16];
#pragma unroll
    for (int r = 0; r < 16; ++r) {
      float d = fmaf(sac[r], -2.f, aq + sqv[r >> 2][r & 3]);
      d = fmaxf(d, 0.f);
      p[r] = EXP2(fmaf(d, rl2, ml2));
    }
    if (dvalid && t == dtile) {                 // diagonal quadrant
#pragma unroll
      for (int r = 0; r < 16; ++r) {
        const int sl = (r & 3) + 8 * (r >> 2) + 4 * hi1;
        if (sl == l31) p[r] = 0.f;
      }
    }

    // PV A-frags in-register (T12)
    const short8 af0 = pack_swap(p[0], p[1], p[2],  p[3],  p[4],  p[5],  p[6],  p[7]);
    const short8 af1 = pack_swap(p[8], p[9], p[10], p[11], p[12], p[13], p[14], p[15]);

#pragma unroll
    for (int ct = 0; ct < 2; ++ct) {
      oacc[ct] = __builtin_amdgcn_mfma_f32_32x32x16_bf16(af0, vf[ct][0], oacc[ct], 0, 0, 0);
      oacc[ct] = __builtin_amdgcn_mfma_f32_32x32x16_bf16(af1, vf[ct][1], oacc[ct], 0, 0, 0);
    }
  }

  // reduce ws halves through LDS; C/D: col c = ct*32+l31, row q = (r&3)+8*(r>>2)+4*hi1
  if (ws == 1) {
#pragma unroll
    for (int ct = 0; ct < 2; ++ct)
#pragma unroll
      for (int r = 0; r < 16; ++r) {
        const int ql = (r & 3) + 8 * (r >> 2) + 4 * hi1;
        Red[wq][ql * 64 + ct * 32 + l31] = oacc[ct][r];
      }
  }
  __syncthreads();
  if (ws == 0) {
#pragma unroll
    for (int ct = 0; ct < 2; ++ct)
#pragma unroll
      for (int r = 0; r < 16; ++r) {
        const int ql = (r & 3) + 8 * (r >> 2) + 4 * hi1;
        const int c  = ct * 32 + l31;
        const size_t idx = (size_t)(b * TT + qb + wq * 32 + ql) * CC + c;
        out[idx] = x[idx] + oacc[ct][r] + Red[wq][ql * 64 + c];
      }
  }
}

// ---------------------------------------------------------------------------
extern "C" void kernel_launch(void* const* d_in, const int* in_sizes, int n_in,
                              void* d_out, int out_size, void* d_ws, size_t ws_size,
                              hipStream_t stream) {
  const float* x    = (const float*)d_in[0];
  const float* rsig = (const float*)d_in[1];
  const float* marg = (const float*)d_in[2];
  float* out = (float*)d_out;

  unsigned short* xb  = (unsigned short*)d_ws;                 // 4 MB
  unsigned short* xbT = xb + (size_t)BB * TT * CC;             // 4 MB
  float* sq = (float*)(xbT + (size_t)BB * TT * CC);            // 128 KB

  prep_kernel<<<2048, 256, 0, stream>>>(x, xb, xbT, sq);
  attn_kernel<<<512, 256, 0, stream>>>(x, xb, xbT, sq, rsig, marg, out);
}

// Round 6
// 109.957 us; speedup vs baseline: 1.2297x; 1.2297x over previous
//
#include <hip/hip_runtime.h>
#include <stdint.h>
#include <stddef.h>

#define BB 16
#define TT 2048
#define CC 64
#define NT 16      // 16 KV tiles of 128

typedef __attribute__((ext_vector_type(8))) short short8;
typedef __attribute__((ext_vector_type(4))) short s16x4;
typedef __attribute__((ext_vector_type(4))) float f32x4;
typedef __attribute__((ext_vector_type(16))) float f32x16;

#if defined(__has_builtin)
#if __has_builtin(__builtin_amdgcn_exp2f)
#define EXP2(x) __builtin_amdgcn_exp2f(x)
#else
#define EXP2(x) exp2f(x)
#endif
#else
#define EXP2(x) exp2f(x)
#endif

// round-to-nearest-even f32 -> bf16 bit pattern
static __device__ __forceinline__ unsigned short f2bf(float f) {
  union { float f; unsigned int u; } v; v.f = f;
  unsigned int u = v.u;
  return (unsigned short)((u + 0x7FFFu + ((u >> 16) & 1u)) >> 16);
}

// T12 pack: 8 f32 (this lane's half of a 16-k strip) -> PV A-fragment.
static __device__ __forceinline__ short8 pack_swap(
    float a0, float a1, float a2, float a3,
    float a4, float a5, float a6, float a7) {
  unsigned X, Z, Y, W;
  asm("v_cvt_pk_bf16_f32 %0, %1, %2" : "=v"(X) : "v"(a0), "v"(a1));
  asm("v_cvt_pk_bf16_f32 %0, %1, %2" : "=v"(Z) : "v"(a2), "v"(a3));
  asm("v_cvt_pk_bf16_f32 %0, %1, %2" : "=v"(Y) : "v"(a4), "v"(a5));
  asm("v_cvt_pk_bf16_f32 %0, %1, %2" : "=v"(W) : "v"(a6), "v"(a7));
  asm("v_permlane32_swap_b32 %0, %1" : "+v"(X), "+v"(Y));
  asm("v_permlane32_swap_b32 %0, %1" : "+v"(Z), "+v"(W));
  union { unsigned u[4]; short8 s; } u;
  u.u[0] = X; u.u[1] = Z; u.u[2] = Y; u.u[3] = W;
  return u.s;
}

// ---------------------------------------------------------------------------
// Prep: xb = bf16(x) [B,T,C]; xbT = transposed [B,C,T]; sq = row sum of sq.
// ---------------------------------------------------------------------------
__global__ __launch_bounds__(256, 4) void prep_kernel(
    const float* __restrict__ x, unsigned short* __restrict__ xb,
    unsigned short* __restrict__ xbT, float* __restrict__ sq)
{
  __shared__ unsigned short tile[16 * 68];
  const int b   = blockIdx.x >> 7;
  const int t0  = (blockIdx.x & 127) << 4;
  const int tid = threadIdx.x;
  const int r   = tid >> 4;
  const int cg  = tid & 15;
  const int c4  = cg * 4;

  const size_t idx = (size_t)(b * TT + t0 + r) * CC + c4;
  const f32x4 v = *(const f32x4*)(x + idx);
  float ssq = v[0]*v[0] + v[1]*v[1] + v[2]*v[2] + v[3]*v[3];

  s16x4 hv;
  hv[0] = (short)f2bf(v[0]); hv[1] = (short)f2bf(v[1]);
  hv[2] = (short)f2bf(v[2]); hv[3] = (short)f2bf(v[3]);
  *(s16x4*)(xb + idx) = hv;
  *(s16x4*)(&tile[r * 68 + c4]) = hv;

  ssq += __shfl_xor(ssq, 1); ssq += __shfl_xor(ssq, 2);
  ssq += __shfl_xor(ssq, 4); ssq += __shfl_xor(ssq, 8);
  if (cg == 0) sq[(size_t)b * TT + t0 + r] = ssq;
  __syncthreads();

  const int c = tid >> 2, tq = tid & 3;
  s16x4 o;
#pragma unroll
  for (int k = 0; k < 4; ++k) o[k] = (short)tile[(tq * 4 + k) * 68 + c];
  *(s16x4*)(xbT + (size_t)(b * CC + c) * TT + t0 + tq * 4) = o;
}

// ---------------------------------------------------------------------------
// attn v4: LDS-staged (v2 structure), scaled up. 512 threads = 8 waves
// (wq 2 x ws 4), block tile 64 q-rows, KV tile 128 s. Swapped QK^T
// (mfma(K,Q), 32x32x16) + T12 in-register P. sq staged in LDS (off the
// dependent chain). Double-buffered K/V, one barrier/tile, 16 tiles.
// Final 4-way ws reduction aliased into the K/V LDS.
// ---------------------------------------------------------------------------
__global__ __launch_bounds__(512, 4) void attn_kernel(
    const float* __restrict__ x, const unsigned short* __restrict__ xb,
    const unsigned short* __restrict__ xbT, const float* __restrict__ sq,
    const float* __restrict__ rsig, const float* __restrict__ marg,
    float* __restrict__ out)
{
  // [buf][ K: 128 s x 64 c (8192) | V^T: 64 c x 128 s (8192) ]
  __shared__ unsigned short SMEM[2][16384];
  __shared__ float SqLds[2][128];

  const int bid = ((blockIdx.x & 7) << 6) | (blockIdx.x >> 3);  // XCD swizzle
  const int b   = bid >> 5;
  const int qb  = (bid & 31) << 6;
  const int tid = threadIdx.x;
  const int w = tid >> 6, lane = tid & 63;
  const int l31 = lane & 31, hi1 = lane >> 5;
  const int wq = w & 1, ws = w >> 1;            // ws in 0..3

  const float L2E = 1.44269504088896f;
  const float rl2 = -rsig[0] * L2E;
  const float ml2 = marg[0] * L2E;

  const unsigned short* xb_b  = xb  + (size_t)b * TT * CC;
  const unsigned short* xbT_b = xbT + (size_t)b * CC * TT;
  const float* sq_b = sq + (size_t)b * TT;

  const int q0w = qb + wq * 32;

  // Q B-fragments: col q = q0w + l31, k = c = kc*16 + hi1*8 + j
  short8 qf[4];
#pragma unroll
  for (int kc = 0; kc < 4; ++kc)
    qf[kc] = *(const short8*)(xb_b + (size_t)(q0w + l31) * CC + kc * 16 + hi1 * 8);
  const float aq = sq_b[q0w + l31];

  f32x16 oacc[2];
#pragma unroll
  for (int ct = 0; ct < 2; ++ct)
#pragma unroll
    for (int i = 0; i < 16; ++i) oacc[ct][i] = 0.f;

  // staging: K rows srowK & srowK+64 (slot 16B), V rows srowV & srowV+32
  const int srowK = tid >> 3, slotK = tid & 7;
  const int swzK  = srowK * 64 + ((slotK ^ (srowK & 7)) * 8);
  const int srowV = tid >> 4, slotV = tid & 15;
  const int swzV  = srowV * 128 + ((slotV ^ (srowV & 7)) * 8);

  short8 sK0, sK1, sV0, sV1;
  f32x4 sS;
  auto LOADT = [&](int t) {
    const size_t tb = (size_t)t * 128;
    sK0 = *(const short8*)(xb_b + (tb + srowK) * CC + slotK * 8);
    sK1 = *(const short8*)(xb_b + (tb + 64 + srowK) * CC + slotK * 8);
    sV0 = *(const short8*)(xbT_b + (size_t)srowV * TT + tb + slotV * 8);
    sV1 = *(const short8*)(xbT_b + (size_t)(srowV + 32) * TT + tb + slotV * 8);
    if (tid < 32) sS = *(const f32x4*)(sq_b + tb + tid * 4);
  };
  auto WRITET = [&](int bf) {
    unsigned short* Kp = &SMEM[bf][0];
    unsigned short* Vp = &SMEM[bf][8192];
    *(short8*)(&Kp[swzK])            = sK0;
    *(short8*)(&Kp[swzK + 64 * 64])  = sK1;
    *(short8*)(&Vp[swzV])            = sV0;
    *(short8*)(&Vp[swzV + 32 * 128]) = sV1;
    if (tid < 32) *(f32x4*)(&SqLds[bf][tid * 4]) = sS;
  };

  LOADT(0); WRITET(0);
  __syncthreads();

  const int rk = ws * 32 + l31;              // local K row (A-frag)
  const int dQ = q0w - ws * 32;              // diagonal ownership
  const int dtile  = dQ >> 7;
  const bool dvalid = ((dQ & 127) == 0) && dtile >= 0 && dtile < NT;

  for (int t = 0; t < NT; ++t) {
    const int cur = t & 1;
    if (t + 1 < NT) LOADT(t + 1);

    const unsigned short* Kp = &SMEM[cur][0];
    const unsigned short* Vp = &SMEM[cur][8192];

    // s sums of squares from LDS (broadcast within lane groups)
    f32x4 sqv[4];
#pragma unroll
    for (int ch = 0; ch < 4; ++ch)
      sqv[ch] = *(const f32x4*)(&SqLds[cur][ws * 32 + ch * 8 + 4 * hi1]);

    // QK^T swapped: D[s][q]
    f32x16 sac;
#pragma unroll
    for (int i = 0; i < 16; ++i) sac[i] = 0.f;
#pragma unroll
    for (int kc = 0; kc < 4; ++kc) {
      const short8 kf = *(const short8*)(
          &Kp[rk * 64 + (((kc * 2 + hi1) ^ (rk & 7)) * 8)]);
      sac = __builtin_amdgcn_mfma_f32_32x32x16_bf16(kf, qf[kc], sac, 0, 0, 0);
    }

    // Gaussian kernel
    float p[16];
#pragma unroll
    for (int r = 0; r < 16; ++r) {
      float d = fmaf(sac[r], -2.f, aq + sqv[r >> 2][r & 3]);
      d = fmaxf(d, 0.f);
      p[r] = EXP2(fmaf(d, rl2, ml2));
    }
    if (dvalid && t == dtile) {              // diagonal quadrant
#pragma unroll
      for (int r = 0; r < 16; ++r) {
        const int sl = (r & 3) + 8 * (r >> 2) + 4 * hi1;
        if (sl == l31) p[r] = 0.f;
      }
    }

    // PV A-frags in-register (T12)
    const short8 af0 = pack_swap(p[0], p[1], p[2],  p[3],  p[4],  p[5],  p[6],  p[7]);
    const short8 af1 = pack_swap(p[8], p[9], p[10], p[11], p[12], p[13], p[14], p[15]);

    // PV: B-frag from V^T rows c, k = s within this wave's 32-s window
#pragma unroll
    for (int ct = 0; ct < 2; ++ct) {
      const int rc = ct * 32 + l31;
#pragma unroll
      for (int kk = 0; kk < 2; ++kk) {
        const short8 vf = *(const short8*)(
            &Vp[rc * 128 + (((ws * 4 + kk * 2 + hi1) ^ (rc & 7)) * 8)]);
        oacc[ct] = __builtin_amdgcn_mfma_f32_32x32x16_bf16(
            kk ? af1 : af0, vf, oacc[ct], 0, 0, 0);
      }
    }

    if (t + 1 < NT) WRITET(cur ^ 1);
    __syncthreads();
  }

  // 4-way ws reduction through LDS (aliased over K/V buffers).
  // C/D: col c = ct*32+l31, row q = (r&3)+8*(r>>2)+4*hi1
  float* RedF = (float*)&SMEM[0][0];         // 6 x 2048 floats = 48 KB
  if (ws != 0) {
    const int base = ((ws - 1) * 2 + wq) * 2048;
#pragma unroll
    for (int ct = 0; ct < 2; ++ct)
#pragma unroll
      for (int r = 0; r < 16; ++r) {
        const int ql = (r & 3) + 8 * (r >> 2) + 4 * hi1;
        RedF[base + ql * 64 + ct * 32 + l31] = oacc[ct][r];
      }
  }
  __syncthreads();
  if (ws == 0) {
#pragma unroll
    for (int ct = 0; ct < 2; ++ct)
#pragma unroll
      for (int r = 0; r < 16; ++r) {
        const int ql = (r & 3) + 8 * (r >> 2) + 4 * hi1;
        const int c  = ct * 32 + l31;
        const int off = ql * 64 + c;
        const size_t idx = (size_t)(b * TT + qb + wq * 32 + ql) * CC + c;
        out[idx] = x[idx] + oacc[ct][r]
                 + RedF[(0 * 2 + wq) * 2048 + off]
                 + RedF[(1 * 2 + wq) * 2048 + off]
                 + RedF[(2 * 2 + wq) * 2048 + off];
      }
  }
}

// ---------------------------------------------------------------------------
extern "C" void kernel_launch(void* const* d_in, const int* in_sizes, int n_in,
                              void* d_out, int out_size, void* d_ws, size_t ws_size,
                              hipStream_t stream) {
  const float* x    = (const float*)d_in[0];
  const float* rsig = (const float*)d_in[1];
  const float* marg = (const float*)d_in[2];
  float* out = (float*)d_out;

  unsigned short* xb  = (unsigned short*)d_ws;                 // 4 MB
  unsigned short* xbT = xb + (size_t)BB * TT * CC;             // 4 MB
  float* sq = (float*)(xbT + (size_t)BB * TT * CC);            // 128 KB

  prep_kernel<<<2048, 256, 0, stream>>>(x, xb, xbT, sq);
  attn_kernel<<<512, 512, 0, stream>>>(x, xb, xbT, sq, rsig, marg, out);
}